// Round 4
// baseline (302.831 us; speedup 1.0000x reference)
//
#include <hip/hip_runtime.h>
#include <stdint.h>

// AttendModule: B=4, C=256, C2=128, T=16, S=256/frame, THW=4096.
// pack_w : W{q,m,v} fp32 -> bf16 once.
// proj   : 3072 waves; wave = (b, 16-p tile, one projection), all 128 o.
//          x-frag software-pipelined across kc; 8 MFMAs per frag.
//          Q,M -> (b,p,c2) bf16; V -> fp32 d_out + bf16 ws (s-permuted so
//          attn phase-2 A-frags are one contiguous dwordx4).
// attn   : wave = (b,t,32q). Streaming no-max softmax over s in chunks of 32.
//          Software-pipelined: V(ch) + M(ch+1) register loads issued before
//          computing ch; raw s_barrier (no vmcnt drain) keeps the block's 4
//          waves L1-aligned. Block swizzle: same-(b,t) blocks -> same XCD.

typedef __attribute__((ext_vector_type(8))) short short8;
typedef __attribute__((ext_vector_type(4))) float float4v;

#define MFMA_BF16_16x16x32(a, b, c) \
  __builtin_amdgcn_mfma_f32_16x16x32_bf16((a), (b), (c), 0, 0, 0)

#if __has_builtin(__builtin_amdgcn_exp2f)
#define EXP2(x) __builtin_amdgcn_exp2f(x)
#else
#define EXP2(x) exp2f(x)
#endif

static constexpr int Bn = 4, Cin = 256, C2 = 128, Tt = 16, THW = 4096;

union Frag8 { short8 s; unsigned u[4]; };

// round-nearest fp32 -> bf16, packed pair
__device__ __forceinline__ unsigned pk2bf(float a, float b) {
  unsigned ua = __float_as_uint(a), ub = __float_as_uint(b);
  ua = (ua + 0x7FFFu + ((ua >> 16) & 1u)) >> 16;
  ub = (ub + 0x7FFFu + ((ub >> 16) & 1u)) & 0xFFFF0000u;
  return ua | ub;
}
__device__ __forceinline__ unsigned short bf16r(float a) {
  unsigned u = __float_as_uint(a);
  return (unsigned short)((u + 0x7FFFu + ((u >> 16) & 1u)) >> 16);
}

// ---------------- Kernel 0: pack W to bf16 ----------------
__global__ __launch_bounds__(256) void pack_w(
    const float* __restrict__ Wq, const float* __restrict__ Wm,
    const float* __restrict__ Wv, short* __restrict__ Wb) {
  const int tid = blockIdx.x * 256 + threadIdx.x;
  const float* srcs[3] = {Wq, Wm, Wv};
  const int proj = tid >> 12;
  const int off = (tid & 4095) * 8;
  const float* s = srcs[proj] + off;
  float4v a = *(const float4v*)s;
  float4v b = *(const float4v*)(s + 4);
  uint4 o;
  o.x = pk2bf(a[0], a[1]); o.y = pk2bf(a[2], a[3]);
  o.z = pk2bf(b[0], b[1]); o.w = pk2bf(b[2], b[3]);
  *(uint4*)(Wb + proj * 32768 + off) = o;
}

// ---------------- Kernel 1: projections ----------------
// 768 blocks x 256 thr = 3072 waves. wave = (proj, b, 16-p tile); all o.
__global__ __launch_bounds__(256) void proj_kernel(
    const float* __restrict__ x, const short* __restrict__ Wb,
    float* __restrict__ Vout, short* __restrict__ Qb,
    short* __restrict__ Mb, short* __restrict__ Vb) {
  const int w = blockIdx.x * 4 + (threadIdx.x >> 6);   // 0..3071
  const int lane = threadIdx.x & 63;
  const int l15 = lane & 15, quad = lane >> 4;
  const int proj = w >> 10;                            // 0..2
  const int b = (w >> 8) & 3;
  const int pt = w & 255;                              // 256 p-tiles/batch
  const int p = pt * 16 + l15;                         // 0..4095

  float4v acc[8];
#pragma unroll
  for (int mt = 0; mt < 8; ++mt) acc[mt] = (float4v){0.f, 0.f, 0.f, 0.f};

  const float* xb = x + ((size_t)b * Cin + quad * 8) * THW + p;
  const short* Wp = Wb + (size_t)proj * C2 * Cin;

  float fc[8], fn[8];
#pragma unroll
  for (int j = 0; j < 8; ++j) fc[j] = xb[(size_t)j * THW];

#pragma unroll
  for (int kc = 0; kc < 8; ++kc) {
    Frag8 bx;
    bx.u[0] = pk2bf(fc[0], fc[1]); bx.u[1] = pk2bf(fc[2], fc[3]);
    bx.u[2] = pk2bf(fc[4], fc[5]); bx.u[3] = pk2bf(fc[6], fc[7]);
    if (kc < 7) {
#pragma unroll
      for (int j = 0; j < 8; ++j) fn[j] = xb[(size_t)((kc + 1) * 32 + j) * THW];
    }
#pragma unroll
    for (int mt = 0; mt < 8; ++mt) {
      short8 wf = *(const short8*)(Wp +
          (size_t)(mt * 16 + l15) * Cin + kc * 32 + quad * 8);
      acc[mt] = MFMA_BF16_16x16x32(wf, bx.s, acc[mt]);
    }
#pragma unroll
    for (int j = 0; j < 8; ++j) fc[j] = fn[j];
  }

  // D layout: col(l15)=p, row(quad*4+r)=o
  if (proj < 2) {
    short* Ob = (proj == 0 ? Qb : Mb) + ((size_t)b * THW + p) * C2;
#pragma unroll
    for (int mt = 0; mt < 8; ++mt) {
      uint2 pq;
      pq.x = pk2bf(acc[mt][0], acc[mt][1]);
      pq.y = pk2bf(acc[mt][2], acc[mt][3]);
      *(uint2*)(Ob + mt * 16 + quad * 4) = pq;
    }
  } else {
    // V fp32 natural (b, o, p) + bf16 with 32-wide s-permutation
    const int pp = (pt >> 1) * 32 + (l15 >> 2) * 8 + (pt & 1) * 4 + (l15 & 3);
#pragma unroll
    for (int mt = 0; mt < 8; ++mt) {
      const int ob = mt * 16 + quad * 4;
#pragma unroll
      for (int r = 0; r < 4; ++r) {
        const float v = acc[mt][r];
        const size_t row = (size_t)(b * C2 + ob + r) * THW;
        Vout[row + p] = v;
        Vb[row + pp] = (short)bf16r(v);
      }
    }
  }
}

// ---------------- Kernel 2: attention ----------------
// 2048 blocks x 256 thr (4 waves). bid swizzled: same (b,t) -> same XCD.
__global__ __launch_bounds__(256) void attn_kernel(
    const short* __restrict__ Qb, const short* __restrict__ Mb,
    const short* __restrict__ Vb, float* __restrict__ Rout) {
  const int bid = blockIdx.x;
  const int qt = bid >> 6;
  const int b = (bid >> 4) & 3;
  const int t = bid & 15;
  const int wv = threadIdx.x >> 6;
  const int lane = threadIdx.x & 63;
  const int l15 = lane & 15, quad = lane >> 4;
  const int q0 = qt * 128 + wv * 32;

  // Q fragments in registers (32 q x 128 c bf16)
  short8 qf[4][2];
#pragma unroll
  for (int kc = 0; kc < 4; ++kc)
#pragma unroll
    for (int n = 0; n < 2; ++n)
      qf[kc][n] = *(const short8*)(Qb +
          ((size_t)b * THW + q0 + n * 16 + l15) * C2 + kc * 32 + quad * 8);

  float4v acc2[8][2];
#pragma unroll
  for (int mt = 0; mt < 8; ++mt) {
    acc2[mt][0] = (float4v){0.f, 0.f, 0.f, 0.f};
    acc2[mt][1] = (float4v){0.f, 0.f, 0.f, 0.f};
  }
  float lsum[2] = {0.f, 0.f};

  const short* Mb0 = Mb + ((size_t)b * THW + t * 256 + l15) * C2 + quad * 8;
  const short* Vb0 = Vb + ((size_t)b * C2 + l15) * THW + t * 256 + quad * 8;
  const float k1 = 0.08838834764831845f * 1.4426950408889634f; // log2e/sqrt(128)

  // ping-pong M-chunk buffers (full unroll renames registers; no copies)
  short8 mbuf[2][2][4];
#pragma unroll
  for (int h = 0; h < 2; ++h)
#pragma unroll
    for (int kc = 0; kc < 4; ++kc)
      mbuf[0][h][kc] = *(const short8*)(Mb0 + (size_t)(h * 16) * C2 + kc * 32);

#pragma unroll
  for (int ch = 0; ch < 8; ++ch) {
    __builtin_amdgcn_s_barrier();   // lockstep only; no vmcnt drain
    const int cur = ch & 1, nxt = cur ^ 1;
    // V loads for this chunk (used at chunk end; latency hidden by S+exp)
    short8 vv[8];
#pragma unroll
    for (int mt = 0; mt < 8; ++mt)
      vv[mt] = *(const short8*)(Vb0 + (size_t)(mt * 16) * THW + ch * 32);
    // M prefetch for next chunk
    if (ch < 7) {
#pragma unroll
      for (int h = 0; h < 2; ++h)
#pragma unroll
        for (int kc = 0; kc < 4; ++kc)
          mbuf[nxt][h][kc] = *(const short8*)(Mb0 +
              (size_t)((ch + 1) * 32 + h * 16) * C2 + kc * 32);
    }
    // S chunk: 32 s x 32 q
    float4v acc[2][2];
    acc[0][0] = (float4v){0.f, 0.f, 0.f, 0.f};
    acc[0][1] = (float4v){0.f, 0.f, 0.f, 0.f};
    acc[1][0] = (float4v){0.f, 0.f, 0.f, 0.f};
    acc[1][1] = (float4v){0.f, 0.f, 0.f, 0.f};
#pragma unroll
    for (int kc = 0; kc < 4; ++kc) {
      acc[0][0] = MFMA_BF16_16x16x32(mbuf[cur][0][kc], qf[kc][0], acc[0][0]);
      acc[0][1] = MFMA_BF16_16x16x32(mbuf[cur][0][kc], qf[kc][1], acc[0][1]);
      acc[1][0] = MFMA_BF16_16x16x32(mbuf[cur][1][kc], qf[kc][0], acc[1][0]);
      acc[1][1] = MFMA_BF16_16x16x32(mbuf[cur][1][kc], qf[kc][1], acc[1][1]);
    }
    // exp (no max: scores ~N(0,0.1)) + pack P as K=32 B-frag
    Frag8 bp[2];
#pragma unroll
    for (int n = 0; n < 2; ++n) {
      float e[8];
#pragma unroll
      for (int mt = 0; mt < 2; ++mt)
#pragma unroll
        for (int r = 0; r < 4; ++r) e[mt * 4 + r] = EXP2(acc[mt][n][r] * k1);
      lsum[n] += ((e[0] + e[1]) + (e[2] + e[3])) + ((e[4] + e[5]) + (e[6] + e[7]));
      bp[n].u[0] = pk2bf(e[0], e[1]); bp[n].u[1] = pk2bf(e[2], e[3]);
      bp[n].u[2] = pk2bf(e[4], e[5]); bp[n].u[3] = pk2bf(e[6], e[7]);
    }
    // acc2 += V * P (K=32, permuted-V dwordx4 A-frags)
#pragma unroll
    for (int mt = 0; mt < 8; ++mt) {
      acc2[mt][0] = MFMA_BF16_16x16x32(vv[mt], bp[0].s, acc2[mt][0]);
      acc2[mt][1] = MFMA_BF16_16x16x32(vv[mt], bp[1].s, acc2[mt][1]);
    }
  }

  // normalize + store: R (b, c2, t_key, q) fp32
  float rl[2];
#pragma unroll
  for (int n = 0; n < 2; ++n) {
    float l = lsum[n];
    l += __shfl_xor(l, 16, 64);
    l += __shfl_xor(l, 32, 64);
    rl[n] = 1.0f / l;
  }
#pragma unroll
  for (int mt = 0; mt < 8; ++mt)
#pragma unroll
    for (int n = 0; n < 2; ++n)
#pragma unroll
      for (int r = 0; r < 4; ++r) {
        const int c = mt * 16 + quad * 4 + r;
        const int q = q0 + n * 16 + l15;
        Rout[(((size_t)b * C2 + c) * Tt + t) * THW + q] = acc2[mt][n][r] * rl[n];
      }
}

extern "C" void kernel_launch(void* const* d_in, const int* in_sizes, int n_in,
                              void* d_out, int out_size, void* d_ws, size_t ws_size,
                              hipStream_t stream) {
  const float* x  = (const float*)d_in[0];
  const float* Wq = (const float*)d_in[1];
  const float* Wm = (const float*)d_in[2];
  const float* Wv = (const float*)d_in[3];

  float* Rout = (float*)d_out;                         // 4*128*16*4096 fp32
  float* Vout = Rout + (size_t)Bn * C2 * Tt * THW;     // + 4*128*4096 fp32

  short* Qb = (short*)d_ws;                            // (b,p,c2) bf16, 4 MB
  short* Mb = Qb + (size_t)Bn * THW * C2;              // (b,p,c2) bf16, 4 MB
  short* Vb = Mb + (size_t)Bn * THW * C2;              // (b,c2,p-perm) bf16, 4 MB
  short* Wb = Vb + (size_t)Bn * C2 * THW;              // (3,128,256) bf16

  pack_w<<<dim3(48), dim3(256), 0, stream>>>(Wq, Wm, Wv, Wb);
  proj_kernel<<<dim3(768), dim3(256), 0, stream>>>(x, Wb, Vout, Qb, Mb, Vb);
  attn_kernel<<<dim3(2048), dim3(256), 0, stream>>>(Qb, Mb, Vb, Rout);
}

// Round 6
// 221.235 us; speedup vs baseline: 1.3688x; 1.3688x over previous
//
#include <hip/hip_runtime.h>
#include <stdint.h>

// AttendModule: B=4, C=256, C2=128, T=16, S=256/frame, THW=4096.
// pack_w : W{q,m,v} fp32 -> bf16 once.
// proj   : 256 blocks; block = (b, 64-p tile) x 256 c x all 3 projections.
//          x staged once through double-buffered LDS slices (32c x 64p fp32)
//          via async global_load_lds; W frags from global (L1-shared).
// attn   : 2048 blocks; block = (b,t,128q), wave = 32 q. Streaming no-max
//          softmax over s in chunks of 32. M chunk (32s x 128c bf16) and
//          V chunk (128c2 x 32s-perm bf16) staged into double-buffered LDS
//          via global_load_lds (each wave stages 1/4 -> zero duplication,
//          4x L2 traffic cut vs per-wave register loads). XOR-swizzled 16B
//          block placement (applied on the global gather address at stage
//          time) makes the M-frag reads (else 16-way) and V-frag reads
//          (else 8-way) 2-way bank-conflict-free.

typedef __attribute__((ext_vector_type(8))) short short8;
typedef __attribute__((ext_vector_type(4))) float float4v;
typedef unsigned int u32;

#define MFMA_BF16_16x16x32(a, b, c) \
  __builtin_amdgcn_mfma_f32_16x16x32_bf16((a), (b), (c), 0, 0, 0)

#if __has_builtin(__builtin_amdgcn_exp2f)
#define EXP2(x) __builtin_amdgcn_exp2f(x)
#else
#define EXP2(x) exp2f(x)
#endif

static constexpr int Bn = 4, Cin = 256, C2 = 128, Tt = 16, THW = 4096;

union Frag8 { short8 s; unsigned u[4]; };

// round-nearest fp32 -> bf16, packed pair
__device__ __forceinline__ unsigned pk2bf(float a, float b) {
  unsigned ua = __float_as_uint(a), ub = __float_as_uint(b);
  ua = (ua + 0x7FFFu + ((ua >> 16) & 1u)) >> 16;
  ub = (ub + 0x7FFFu + ((ub >> 16) & 1u)) & 0xFFFF0000u;
  return ua | ub;
}
__device__ __forceinline__ unsigned short bf16r(float a) {
  unsigned u = __float_as_uint(a);
  return (unsigned short)((u + 0x7FFFu + ((u >> 16) & 1u)) >> 16);
}

// async global->LDS, 16 B per lane. lds_base must be wave-uniform; HW writes
// lds_base + lane*16. gptr is per-lane (gather).
__device__ __forceinline__ void gl2lds16(const void* g, void* lds_base) {
#if __has_builtin(__builtin_amdgcn_global_load_lds)
  __builtin_amdgcn_global_load_lds(
      (const __attribute__((address_space(1))) u32*)g,
      (__attribute__((address_space(3))) u32*)lds_base, 16, 0, 0);
#else
  ((uint4*)lds_base)[threadIdx.x & 63] = *(const uint4*)g;
#endif
}

// ---------------- Kernel 0: pack W to bf16 ----------------
__global__ __launch_bounds__(256) void pack_w(
    const float* __restrict__ Wq, const float* __restrict__ Wm,
    const float* __restrict__ Wv, short* __restrict__ Wb) {
  const int tid = blockIdx.x * 256 + threadIdx.x;
  const float* srcs[3] = {Wq, Wm, Wv};
  const int proj = tid >> 12;
  const int off = (tid & 4095) * 8;
  const float* s = srcs[proj] + off;
  float4v a = *(const float4v*)s;
  float4v b = *(const float4v*)(s + 4);
  uint4 o;
  o.x = pk2bf(a[0], a[1]); o.y = pk2bf(a[2], a[3]);
  o.z = pk2bf(b[0], b[1]); o.w = pk2bf(b[2], b[3]);
  *(uint4*)(Wb + proj * 32768 + off) = o;
}

// ---------------- Kernel 1: projections ----------------
// 256 blocks x 256 thr. block = (b, 64-p tile); wave wv covers p sub-tile.
__global__ __launch_bounds__(256) void proj_kernel(
    const float* __restrict__ x, const short* __restrict__ Wb,
    float* __restrict__ Vout, short* __restrict__ Qb,
    short* __restrict__ Mb, short* __restrict__ Vb) {
  __shared__ __align__(16) float Xl[2][2048];   // 2 x 8KB: [32 c][64 p]

  const int bid = blockIdx.x;
  const int b = bid >> 6;
  const int pt64 = bid & 63;
  const int p0 = pt64 * 64;
  const int wv = (int)(threadIdx.x >> 6);
  const int lane = (int)(threadIdx.x & 63);
  const int l15 = lane & 15, quad = lane >> 4;
  const int p = p0 + wv * 16 + l15;

  float4v acc[3][8];
#pragma unroll
  for (int pr = 0; pr < 3; ++pr)
#pragma unroll
    for (int mt = 0; mt < 8; ++mt) acc[pr][mt] = (float4v){0.f, 0.f, 0.f, 0.f};

  // stage slice kc (32 c x 64 p fp32 = 8 KB) into Xl[bi]
  const int srow0 = (int)(threadIdx.x >> 4);
  const int srow[2] = {srow0, 16 + srow0};
  const int sseg = lane & 15;   // 16B unit within the 256B row
  const float* xb = x + (size_t)b * Cin * THW + p0;

#define STAGE_X(bi, kc)                                                     \
  {                                                                         \
    _Pragma("unroll") for (int i = 0; i < 2; ++i) {                         \
      const float* g = xb + (size_t)((kc) * 32 + srow[i]) * THW + sseg * 4; \
      gl2lds16(g, &Xl[bi][i * 1024 + wv * 256]);                            \
    }                                                                       \
  }

  STAGE_X(0, 0);
  __syncthreads();

  for (int kc = 0; kc < 8; ++kc) {
    const int cur = kc & 1;
    if (kc < 7) STAGE_X(cur ^ 1, kc + 1);
    // B-frag: x[c=quad*8+j][p] from LDS (8 x ds_read_b32, ~4-way)
    float f[8];
#pragma unroll
    for (int j = 0; j < 8; ++j)
      f[j] = Xl[cur][(quad * 8 + j) * 64 + wv * 16 + l15];
    Frag8 bx;
    bx.u[0] = pk2bf(f[0], f[1]); bx.u[1] = pk2bf(f[2], f[3]);
    bx.u[2] = pk2bf(f[4], f[5]); bx.u[3] = pk2bf(f[6], f[7]);
#pragma unroll
    for (int pr = 0; pr < 3; ++pr)
#pragma unroll
      for (int mt = 0; mt < 8; ++mt) {
        short8 wf = *(const short8*)(Wb +
            ((size_t)pr * C2 + mt * 16 + l15) * Cin + kc * 32 + quad * 8);
        acc[pr][mt] = MFMA_BF16_16x16x32(wf, bx.s, acc[pr][mt]);
      }
    __syncthreads();
  }
#undef STAGE_X

  // D layout: col(l15)=p, row(quad*4+r)=o
  short* qrow = Qb + ((size_t)b * THW + p) * C2;
  short* mrow = Mb + ((size_t)b * THW + p) * C2;
  const int pt = pt64 * 4 + wv;
  const int pp = (pt >> 1) * 32 + (l15 >> 2) * 8 + (pt & 1) * 4 + (l15 & 3);
#pragma unroll
  for (int mt = 0; mt < 8; ++mt) {
    const int ob = mt * 16 + quad * 4;
    uint2 pq, pm;
    pq.x = pk2bf(acc[0][mt][0], acc[0][mt][1]);
    pq.y = pk2bf(acc[0][mt][2], acc[0][mt][3]);
    pm.x = pk2bf(acc[1][mt][0], acc[1][mt][1]);
    pm.y = pk2bf(acc[1][mt][2], acc[1][mt][3]);
    *(uint2*)(qrow + ob) = pq;
    *(uint2*)(mrow + ob) = pm;
#pragma unroll
    for (int r = 0; r < 4; ++r) {
      const float v = acc[2][mt][r];
      const size_t row = (size_t)(b * C2 + ob + r) * THW;
      Vout[row + p] = v;
      Vb[row + pp] = (short)bf16r(v);
    }
  }
}

// ---------------- Kernel 2: attention ----------------
// 2048 blocks x 256 thr (4 waves). bid: same-(b,t) blocks -> same XCD.
__global__ __launch_bounds__(256) void attn_kernel(
    const short* __restrict__ Qb, const short* __restrict__ Mb,
    const short* __restrict__ Vb, float* __restrict__ Rout) {
  __shared__ __align__(16) short Ml[2][4096];  // [32 s][128 c], blk-swizzled
  __shared__ __align__(16) short Vl[2][4096];  // [128 c2][32 s-perm], swizzled

  const int bid = blockIdx.x;
  const int qt = bid >> 6;
  const int b = (bid >> 4) & 3;
  const int t = bid & 15;
  const int wv = (int)(threadIdx.x >> 6);
  const int lane = (int)(threadIdx.x & 63);
  const int l15 = lane & 15, quad = lane >> 4;
  const int q0 = qt * 128 + wv * 32;

  // staging lane constants. LDS 16B-block l = i*256 + wv*64 + lane.
  // M: LDS block l holds global block g = (l&~15) | ((l ^ (l>>4)) & 15)
  // V: LDS block c2*4+blk' holds global blk = blk' ^ ((c2 + (c2>>2)) & 3)
  int mg[2], vc2[2], vblk[2];
#pragma unroll
  for (int i = 0; i < 2; ++i) {
    const int l = i * 256 + wv * 64 + lane;
    mg[i] = (l & ~15) | ((l ^ (l >> 4)) & 15);
    const int c2 = l >> 2;
    vc2[i] = c2;
    vblk[i] = (l & 3) ^ ((c2 + (c2 >> 2)) & 3);
  }
  const short* Mchunk0 = Mb + ((size_t)b * THW + t * 256) * C2;
  const short* Vrow0 = Vb + (size_t)b * C2 * THW + t * 256;

#define STAGE_MV(bi, ch)                                                      \
  {                                                                           \
    _Pragma("unroll") for (int i = 0; i < 2; ++i) {                           \
      gl2lds16(Mchunk0 + (size_t)(ch) * 32 * C2 + mg[i] * 8,                  \
               &Ml[bi][(i * 256 + wv * 64) * 8]);                             \
      gl2lds16(Vrow0 + (size_t)vc2[i] * THW + (ch) * 32 + vblk[i] * 8,        \
               &Vl[bi][(i * 256 + wv * 64) * 8]);                             \
    }                                                                         \
  }

  // Q frags in registers (32 q x 128 c bf16)
  short8 qf[4][2];
#pragma unroll
  for (int kc = 0; kc < 4; ++kc)
#pragma unroll
    for (int n = 0; n < 2; ++n)
      qf[kc][n] = *(const short8*)(Qb +
          ((size_t)b * THW + q0 + n * 16 + l15) * C2 + kc * 32 + quad * 8);

  float4v acc2[8][2];
#pragma unroll
  for (int mt = 0; mt < 8; ++mt) {
    acc2[mt][0] = (float4v){0.f, 0.f, 0.f, 0.f};
    acc2[mt][1] = (float4v){0.f, 0.f, 0.f, 0.f};
  }
  float lsum[2] = {0.f, 0.f};
  const float k1 = 0.08838834764831845f * 1.4426950408889634f; // log2e/sqrt128

  STAGE_MV(0, 0);
  __syncthreads();

  for (int ch = 0; ch < 8; ++ch) {
    const int cur = ch & 1;
    if (ch < 7) STAGE_MV(cur ^ 1, ch + 1);

    // ---- S chunk: 32 s x 32 q. A-frag: M[s=h*16+l15][c=kc*32+quad*8..] ----
    float4v sacc[2][2];
    sacc[0][0] = (float4v){0.f, 0.f, 0.f, 0.f};
    sacc[0][1] = (float4v){0.f, 0.f, 0.f, 0.f};
    sacc[1][0] = (float4v){0.f, 0.f, 0.f, 0.f};
    sacc[1][1] = (float4v){0.f, 0.f, 0.f, 0.f};
#pragma unroll
    for (int kc = 0; kc < 4; ++kc)
#pragma unroll
      for (int h = 0; h < 2; ++h) {
        const int row = h * 16 + l15;
        const int lblk = row * 16 + ((kc * 4 + quad) ^ (row & 15));
        short8 am = *(const short8*)&Ml[cur][lblk * 8];
        sacc[h][0] = MFMA_BF16_16x16x32(am, qf[kc][0], sacc[h][0]);
        sacc[h][1] = MFMA_BF16_16x16x32(am, qf[kc][1], sacc[h][1]);
      }

    // ---- exp (no max: scores ~N(0,0.1)) + pack P as K=32 B-frag ----
    Frag8 bp[2];
#pragma unroll
    for (int n = 0; n < 2; ++n) {
      float e[8];
#pragma unroll
      for (int h = 0; h < 2; ++h)
#pragma unroll
        for (int r = 0; r < 4; ++r) e[h * 4 + r] = EXP2(sacc[h][n][r] * k1);
      lsum[n] += ((e[0] + e[1]) + (e[2] + e[3])) + ((e[4] + e[5]) + (e[6] + e[7]));
      bp[n].u[0] = pk2bf(e[0], e[1]); bp[n].u[1] = pk2bf(e[2], e[3]);
      bp[n].u[2] = pk2bf(e[4], e[5]); bp[n].u[3] = pk2bf(e[6], e[7]);
    }

    // ---- acc2 += V * P. A-frag: V[c2=mt*16+l15][s-perm block quad] ----
#pragma unroll
    for (int mt = 0; mt < 8; ++mt) {
      const int c2 = mt * 16 + l15;
      const int vb = quad ^ ((c2 + (c2 >> 2)) & 3);
      short8 av = *(const short8*)&Vl[cur][(c2 * 4 + vb) * 8];
      acc2[mt][0] = MFMA_BF16_16x16x32(av, bp[0].s, acc2[mt][0]);
      acc2[mt][1] = MFMA_BF16_16x16x32(av, bp[1].s, acc2[mt][1]);
    }
    __syncthreads();
  }
#undef STAGE_MV

  // ---- normalize + store: R (b, c2, t_key, q) fp32 ----
  float rl[2];
#pragma unroll
  for (int n = 0; n < 2; ++n) {
    float l = lsum[n];
    l += __shfl_xor(l, 16, 64);
    l += __shfl_xor(l, 32, 64);
    rl[n] = 1.0f / l;
  }
#pragma unroll
  for (int mt = 0; mt < 8; ++mt)
#pragma unroll
    for (int n = 0; n < 2; ++n)
#pragma unroll
      for (int r = 0; r < 4; ++r) {
        const int c = mt * 16 + quad * 4 + r;
        const int q = q0 + n * 16 + l15;
        Rout[(((size_t)b * C2 + c) * Tt + t) * THW + q] = acc2[mt][n][r] * rl[n];
      }
}

extern "C" void kernel_launch(void* const* d_in, const int* in_sizes, int n_in,
                              void* d_out, int out_size, void* d_ws, size_t ws_size,
                              hipStream_t stream) {
  const float* x  = (const float*)d_in[0];
  const float* Wq = (const float*)d_in[1];
  const float* Wm = (const float*)d_in[2];
  const float* Wv = (const float*)d_in[3];

  float* Rout = (float*)d_out;                         // 4*128*16*4096 fp32
  float* Vout = Rout + (size_t)Bn * C2 * Tt * THW;     // + 4*128*4096 fp32

  short* Qb = (short*)d_ws;                            // (b,p,c2) bf16, 4 MB
  short* Mb = Qb + (size_t)Bn * THW * C2;              // (b,p,c2) bf16, 4 MB
  short* Vb = Mb + (size_t)Bn * THW * C2;              // (b,c2,p-perm) bf16, 4 MB
  short* Wb = Vb + (size_t)Bn * C2 * THW;              // (3,128,256) bf16

  pack_w<<<dim3(48), dim3(256), 0, stream>>>(Wq, Wm, Wv, Wb);
  proj_kernel<<<dim3(256), dim3(256), 0, stream>>>(x, Wb, Vout, Qb, Mb, Vb);
  attn_kernel<<<dim3(2048), dim3(256), 0, stream>>>(Qb, Mb, Vb, Rout);
}